// Round 13
// baseline (107.967 us; speedup 1.0000x reference)
//
#include <hip/hip_runtime.h>
#include <hip/hip_fp16.h>

#define NREZ 256
#define NB 8
#define NA 180

// guarded interleaved source: 258x258 pixels of 16B (8 x fp16), 1-px zero border
#define GW 258
#define GBYTES ((size_t)GW * GW * 16)  /* 1,065,024 B */

// LDS tile: 47 rows x LWr-pixel stride, LWr chosen PER ANGLE from [47,52] so the
// per-lane address step sigma = sn*LWr + cs (pixels of 16B) is far from even mod 2
// -> 32 linear-stepping lanes spread ~uniformly over the 8 bank groups. (R10-best)
#define LWMAX 52
#define LH 47
#define CHUNK_T 32
#define NCHUNK (NREZ / CHUNK_T)

__device__ __forceinline__ __half2 bc_h2(unsigned int v) {
    return __builtin_bit_cast(__half2, v);
}

__device__ __forceinline__ void dma16(const uint4* g, uint4* l) {
    // wave-uniform LDS base; HW scatters active lane i to base + i*16 (verified R6-R12)
    __builtin_amdgcn_global_load_lds(
        (const __attribute__((address_space(1))) void*)g,
        (__attribute__((address_space(3))) void*)l, 16, 0, 0);
}

// interleave 8 batches -> fp16 uint4 pixel at guard offset (+1,+1); border -> 0
__global__ __launch_bounds__(256) void build_fp16g(const float* __restrict__ img,
                                                   uint4* __restrict__ gbuf) {
    const int gy = blockIdx.x;  // 0..257
    for (int gx = threadIdx.x; gx < GW; gx += 256) {
        uint4 v = make_uint4(0u, 0u, 0u, 0u);
        const int x = gx - 1, y = gy - 1;
        if (x >= 0 && x < NREZ && y >= 0 && y < NREZ) {
            const int p = (y << 8) + x;
            unsigned short h[NB];
#pragma unroll
            for (int b = 0; b < NB; ++b)
                h[b] = __half_as_ushort(__float2half_rn(img[b * (NREZ * NREZ) + p]));
            v.x = (unsigned)h[0] | ((unsigned)h[1] << 16);
            v.y = (unsigned)h[2] | ((unsigned)h[3] << 16);
            v.z = (unsigned)h[4] | ((unsigned)h[5] << 16);
            v.w = (unsigned)h[6] | ((unsigned)h[7] << 16);
        }
        gbuf[(size_t)gy * GW + gx] = v;
    }
}

__global__ __launch_bounds__(256, 4) void radon_dma(const uint4* __restrict__ gbuf,
                                                    const float* __restrict__ angles,
                                                    float* __restrict__ out) {
    __shared__ uint4 tile[LWMAX * LH];  // 39,104 B -> 4 blocks/CU (16 waves)

    const int a = blockIdx.x;
    const int tid = threadIdx.x;
    const int wave = tid >> 6;
    const int lane = tid & 63;
    const int ls = lane & 31;   // s within the block's 32-s strip
    const int lp = lane >> 5;   // t phase (0/1)
    const int sIdx = blockIdx.y * 32 + ls;
    const int tw = 2 * wave + lp;  // t-offset 0..7; samples tt = t_lo + tw + 8*it

    const float C = 127.5f;
    float sn, cs;
    sincosf(angles[a], &sn, &cs);

    // per-angle row stride: maximize margin of (sn*LW + cs) mod 2 from even
    int LWr = 47;
    {
        float best = -1.f;
#pragma unroll
        for (int w = 47; w <= LWMAX; ++w) {
            const float sig = fmaf(sn, (float)w, cs);
            const float u = sig - 2.f * floorf(sig * 0.5f);  // [0,2)
            const float m = 1.f - fabsf(u - 1.f);            // 1 = odd (perfect)
            if (m > best) { best = m; LWr = w; }
        }
    }

    const float s = (float)sIdx - C;
    const float xs = fmaf(s, cs, C);  // x = fmaf(tt,-sn,xs)
    const float ys = fmaf(s, sn, C);  // y = fmaf(tt, cs,ys)

    // block-uniform s extremes; SAME fmaf chain as per-lane math (fp-monotone)
    const float s_lo = (float)(blockIdx.y * 32) - C;
    const float s_hi = s_lo + 31.f;
    const float xsl = fmaf(s_lo, cs, C), xsh = fmaf(s_hi, cs, C);
    const float ysl = fmaf(s_lo, sn, C), ysh = fmaf(s_hi, sn, C);

    // bbox of chunk ck: corner span <= 31(|cs|+|sn|) <= 43.9 -> u0,v0 in [b?, b?+44],
    // +1 corner -> 46 px; 47 staged cols/rows cover all cases incl. edge clamps.
    auto window = [&](int ck, int& bxs, int& bys, bool& interior) {
        const float t_lo = (float)(ck * CHUNK_T) - C;
        const float t_hi = t_lo + 31.f;
        const float x00 = fmaf(t_lo, -sn, xsl), x01 = fmaf(t_hi, -sn, xsl);
        const float x10 = fmaf(t_lo, -sn, xsh), x11 = fmaf(t_hi, -sn, xsh);
        const float y00 = fmaf(t_lo, cs, ysl), y01 = fmaf(t_hi, cs, ysl);
        const float y10 = fmaf(t_lo, cs, ysh), y11 = fmaf(t_hi, cs, ysh);
        const int bx = (int)floorf(fminf(fminf(x00, x01), fminf(x10, x11)));
        const int by = (int)floorf(fminf(fminf(y00, y01), fminf(y10, y11)));
        bxs = min(max(bx, -1), 210);
        bys = min(max(by, -1), 210);
        interior = (bx >= 0) && (by >= 0) && (bx <= 210) && (by <= 210);
    };

    // stage 47 rows x 47 cols; gx,gy in [0,257] of padded source by construction
    auto stage = [&](int bxs, int bys) {
#pragma unroll
        for (int k = 0; k < 12; ++k) {
            const int row = wave + 4 * k;  // 0..47
            if (row < LH && lane < 47) {
                const uint4* gp = gbuf + (size_t)(bys + row + 1) * GW + (bxs + 1) + lane;
                dma16(gp, &tile[row * LWr]);
            }
        }
    };

    float accf[NB];
#pragma unroll
    for (int b = 0; b < NB; ++b) accf[b] = 0.f;
    const __half2 hz = __float2half2_rn(0.f);

    int bxs, bys;
    bool interior;
    window(0, bxs, bys, interior);
    stage(bxs, bys);

    for (int ck = 0; ck < NCHUNK; ++ck) {
        __syncthreads();  // DMA of chunk ck drained

        const float t_lo = (float)(ck * CHUNK_T) - C;
        __half2 acc01 = hz, acc23 = hz, acc45 = hz, acc67 = hz;

        // ---- phase 1: branchless indices + masked weights for all 4 samples ----
        __half2 W00[4], W10[4], W01[4], W11[4];
        int B00[4];
        const bool chk = !interior;
#pragma unroll
        for (int it = 0; it < 4; ++it) {
            const float tt = t_lo + (float)(tw + 8 * it);
            const float x = fmaf(tt, -sn, xs);
            const float y = fmaf(tt, cs, ys);
            const float xf = floorf(x), yf = floorf(y);
            const int u0 = (int)xf, v0 = (int)yf;
            const bool ok =
                !chk || (u0 >= -1 && u0 <= 255 && v0 >= -1 && v0 <= 255);
            const float m = ok ? 1.f : 0.f;  // OOB sample contributes 0 (ref semantics)
            const float wu = x - xf, wv = y - yf;
            const float au = 1.f - wu, av = 1.f - wv;
            W00[it] = __float2half2_rn(au * av * m);
            W10[it] = __float2half2_rn(wu * av * m);
            W01[it] = __float2half2_rn(au * wv * m);
            W11[it] = __float2half2_rn(wu * wv * m);
            const int dx = u0 - bxs;  // in [0,45] when ok
            const int r = v0 - bys;   // in [0,45] when ok
            B00[it] = ok ? (r * LWr + dx) : 0;  // OOB -> harmless read of tile[0]
        }

        // ---- phase 2: issue all 16 independent ds_read_b128 ----
        uint4 P[4][4];
#pragma unroll
        for (int it = 0; it < 4; ++it) {
            P[it][0] = tile[B00[it]];
            P[it][1] = tile[B00[it] + 1];
            P[it][2] = tile[B00[it] + LWr];
            P[it][3] = tile[B00[it] + LWr + 1];
        }

        // ---- phase 3: 64 packed FMAs ----
#pragma unroll
        for (int it = 0; it < 4; ++it) {
            acc01 = __hfma2(W00[it], bc_h2(P[it][0].x), acc01);
            acc01 = __hfma2(W10[it], bc_h2(P[it][1].x), acc01);
            acc01 = __hfma2(W01[it], bc_h2(P[it][2].x), acc01);
            acc01 = __hfma2(W11[it], bc_h2(P[it][3].x), acc01);
            acc23 = __hfma2(W00[it], bc_h2(P[it][0].y), acc23);
            acc23 = __hfma2(W10[it], bc_h2(P[it][1].y), acc23);
            acc23 = __hfma2(W01[it], bc_h2(P[it][2].y), acc23);
            acc23 = __hfma2(W11[it], bc_h2(P[it][3].y), acc23);
            acc45 = __hfma2(W00[it], bc_h2(P[it][0].z), acc45);
            acc45 = __hfma2(W10[it], bc_h2(P[it][1].z), acc45);
            acc45 = __hfma2(W01[it], bc_h2(P[it][2].z), acc45);
            acc45 = __hfma2(W11[it], bc_h2(P[it][3].z), acc45);
            acc67 = __hfma2(W00[it], bc_h2(P[it][0].w), acc67);
            acc67 = __hfma2(W10[it], bc_h2(P[it][1].w), acc67);
            acc67 = __hfma2(W01[it], bc_h2(P[it][2].w), acc67);
            acc67 = __hfma2(W11[it], bc_h2(P[it][3].w), acc67);
        }

        accf[0] += __low2float(acc01); accf[1] += __high2float(acc01);
        accf[2] += __low2float(acc23); accf[3] += __high2float(acc23);
        accf[4] += __low2float(acc45); accf[5] += __high2float(acc45);
        accf[6] += __low2float(acc67); accf[7] += __high2float(acc67);

        __syncthreads();  // all reads of chunk ck done; safe to overwrite tile

        if (ck + 1 < NCHUNK) {
            window(ck + 1, bxs, bys, interior);
            stage(bxs, bys);
        }
    }

    // ---- reduction: t-phase pair within wave, then 4 waves via LDS ----
#pragma unroll
    for (int b = 0; b < NB; ++b) accf[b] += __shfl_xor(accf[b], 32);

    float4* red4 = (float4*)tile;  // 4 waves x 32 s x 8 b = 4 KB, tile is free
    if (lane < 32) {
        red4[(wave * 32 + lane) * 2 + 0] = make_float4(accf[0], accf[1], accf[2], accf[3]);
        red4[(wave * 32 + lane) * 2 + 1] = make_float4(accf[4], accf[5], accf[6], accf[7]);
    }
    __syncthreads();
    {
        const float* red = (const float*)tile;
        const int b = tid >> 5;   // 0..7
        const int ss = tid & 31;  // 0..31
        const int base = ss * 8 + b;
        const float sum = red[base] + red[256 + base] + red[512 + base] + red[768 + base];
        out[(b * NA + a) * NREZ + blockIdx.y * 32 + ss] = sum;
    }
}

// -------- fallback (ws too small): direct fp32 gather with clamps --------
__global__ __launch_bounds__(256) void radon_plain(const float* __restrict__ img,
                                                   const float* __restrict__ angles,
                                                   float* __restrict__ out) {
    const int a = blockIdx.x;
    const int tid = threadIdx.x;
    const int wave = tid >> 6;
    const int lane = tid & 63;
    const int s_sub = lane & 7;
    const int t_sub = lane >> 3;
    const int sIdx = blockIdx.y * 32 + wave * 8 + s_sub;
    const float c = 127.5f;
    float sn, cs;
    sincosf(angles[a], &sn, &cs);
    const float s = (float)sIdx - c;
    float acc[NB];
#pragma unroll
    for (int b = 0; b < NB; ++b) acc[b] = 0.f;
    for (int j = 0; j < NREZ / 8; ++j) {
        const float tt = (float)(t_sub + 8 * j) - c;
        const float x = s * cs - tt * sn + c;
        const float y = s * sn + tt * cs + c;
        const float xf = floorf(x), yf = floorf(y);
        const int u0 = (int)xf, v0 = (int)yf;
        if (u0 < -1 || u0 >= NREZ || v0 < -1 || v0 >= NREZ) continue;
        const float wu = x - xf, wv = y - yf;
        const bool iu0 = (u0 >= 0), iu1 = (u0 + 1 <= NREZ - 1);
        const bool iv0 = (v0 >= 0), iv1 = (v0 + 1 <= NREZ - 1);
        const float w00 = (1.f - wu) * (1.f - wv) * ((iu0 && iv0) ? 1.f : 0.f);
        const float w10 = wu * (1.f - wv) * ((iu1 && iv0) ? 1.f : 0.f);
        const float w01 = (1.f - wu) * wv * ((iu0 && iv1) ? 1.f : 0.f);
        const float w11 = wu * wv * ((iu1 && iv1) ? 1.f : 0.f);
        const int u0c = min(max(u0, 0), NREZ - 1);
        const int u1c = min(u0 + 1, NREZ - 1);
        const int v0c = min(max(v0, 0), NREZ - 1);
        const int v1c = min(v0 + 1, NREZ - 1);
#pragma unroll
        for (int b = 0; b < NB; ++b) {
            const float* p = img + b * (NREZ * NREZ);
            acc[b] += w00 * p[v0c * NREZ + u0c] + w10 * p[v0c * NREZ + u1c] +
                      w01 * p[v1c * NREZ + u0c] + w11 * p[v1c * NREZ + u1c];
        }
    }
#pragma unroll
    for (int b = 0; b < NB; ++b) {
        float v = acc[b];
        v += __shfl_xor(v, 8);
        v += __shfl_xor(v, 16);
        v += __shfl_xor(v, 32);
        acc[b] = v;
    }
    if (t_sub == 0) {
#pragma unroll
        for (int b = 0; b < NB; ++b) out[(b * NA + a) * NREZ + sIdx] = acc[b];
    }
}

extern "C" void kernel_launch(void* const* d_in, const int* in_sizes, int n_in,
                              void* d_out, int out_size, void* d_ws, size_t ws_size,
                              hipStream_t stream) {
    (void)in_sizes; (void)n_in; (void)out_size;
    const float* imgs = (const float*)d_in[0];
    const float* angles = (const float*)d_in[1];
    float* out = (float*)d_out;

    dim3 grid(NA, NREZ / 32);
    if (ws_size >= GBYTES) {
        uint4* gbuf = (uint4*)d_ws;
        build_fp16g<<<GW, 256, 0, stream>>>(imgs, gbuf);  // fused guard-zeroing
        radon_dma<<<grid, 256, 0, stream>>>(gbuf, angles, out);
    } else {
        radon_plain<<<grid, 256, 0, stream>>>(imgs, angles, out);
    }
}

// Round 14
// 91.007 us; speedup vs baseline: 1.1864x; 1.1864x over previous
//
#include <hip/hip_runtime.h>
#include <hip/hip_fp16.h>

#define NREZ 256
#define NB 8
#define NA 180

// guarded interleaved source: 258x258 pixels of 16B (8 x fp16), 1-px zero border
#define GW 258
#define GBYTES ((size_t)GW * GW * 16)  /* 1,065,024 B */

// LDS tile: 47 rows x LWr-pixel stride, LWr chosen PER ANGLE from [47,52] so the
// per-lane address step sigma = sn*LWr + cs (pixels of 16B) is far from even mod 2
// -> 32 linear-stepping lanes spread ~uniformly over the 8 bank groups. (R10-best)
#define LWMAX 52
#define LH 47
#define CHUNK_T 32
#define NCHUNK (NREZ / CHUNK_T)

__device__ __forceinline__ __half2 bc_h2(unsigned int v) {
    return __builtin_bit_cast(__half2, v);
}

__device__ __forceinline__ void dma16(const uint4* g, uint4* l) {
    // wave-uniform LDS base; HW scatters active lane i to base + i*16 (verified R6-R13)
    __builtin_amdgcn_global_load_lds(
        (const __attribute__((address_space(1))) void*)g,
        (__attribute__((address_space(3))) void*)l, 16, 0, 0);
}

// interleave 8 batches -> fp16 uint4 pixel at guard offset (+1,+1); border -> 0
__global__ __launch_bounds__(256) void build_fp16g(const float* __restrict__ img,
                                                   uint4* __restrict__ gbuf) {
    const int gy = blockIdx.x;  // 0..257
    for (int gx = threadIdx.x; gx < GW; gx += 256) {
        uint4 v = make_uint4(0u, 0u, 0u, 0u);
        const int x = gx - 1, y = gy - 1;
        if (x >= 0 && x < NREZ && y >= 0 && y < NREZ) {
            const int p = (y << 8) + x;
            unsigned short h[NB];
#pragma unroll
            for (int b = 0; b < NB; ++b)
                h[b] = __half_as_ushort(__float2half_rn(img[b * (NREZ * NREZ) + p]));
            v.x = (unsigned)h[0] | ((unsigned)h[1] << 16);
            v.y = (unsigned)h[2] | ((unsigned)h[3] << 16);
            v.z = (unsigned)h[4] | ((unsigned)h[5] << 16);
            v.w = (unsigned)h[6] | ((unsigned)h[7] << 16);
        }
        gbuf[(size_t)gy * GW + gx] = v;
    }
}

__global__ __launch_bounds__(256, 4) void radon_dma(const uint4* __restrict__ gbuf,
                                                    const float* __restrict__ angles,
                                                    float* __restrict__ out) {
    __shared__ uint4 tile[LWMAX * LH];  // 39,104 B -> 4 blocks/CU (16 waves)

    const int a = blockIdx.x;
    const int tid = threadIdx.x;
    const int wave = tid >> 6;
    const int lane = tid & 63;
    const int ls = lane & 31;   // s within the block's 32-s strip
    const int lp = lane >> 5;   // t phase (0/1)
    const int sIdx = blockIdx.y * 32 + ls;
    const int tw = 2 * wave + lp;  // t-offset 0..7; samples tt = t_lo + tw + 8*it

    const float C = 127.5f;
    float sn, cs;
    sincosf(angles[a], &sn, &cs);

    // per-angle row stride: maximize margin of (sn*LW + cs) mod 2 from even
    int LWr = 47;
    {
        float best = -1.f;
#pragma unroll
        for (int w = 47; w <= LWMAX; ++w) {
            const float sig = fmaf(sn, (float)w, cs);
            const float u = sig - 2.f * floorf(sig * 0.5f);  // [0,2)
            const float m = 1.f - fabsf(u - 1.f);            // 1 = odd (perfect)
            if (m > best) { best = m; LWr = w; }
        }
    }

    const float s = (float)sIdx - C;
    const float xs = fmaf(s, cs, C);  // x = fmaf(tt,-sn,xs)
    const float ys = fmaf(s, sn, C);  // y = fmaf(tt, cs,ys)

    // block-uniform s extremes; SAME fmaf chain as per-lane math (fp-monotone)
    const float s_lo = (float)(blockIdx.y * 32) - C;
    const float s_hi = s_lo + 31.f;
    const float xsl = fmaf(s_lo, cs, C), xsh = fmaf(s_hi, cs, C);
    const float ysl = fmaf(s_lo, sn, C), ysh = fmaf(s_hi, sn, C);

    // bbox of chunk ck: corner span <= 31(|cs|+|sn|) <= 43.9 -> u0,v0 in [b?, b?+44],
    // +1 corner -> 46 px; 47 staged cols/rows cover all cases incl. edge clamps.
    auto window = [&](int ck, int& bxs, int& bys, bool& interior) {
        const float t_lo = (float)(ck * CHUNK_T) - C;
        const float t_hi = t_lo + 31.f;
        const float x00 = fmaf(t_lo, -sn, xsl), x01 = fmaf(t_hi, -sn, xsl);
        const float x10 = fmaf(t_lo, -sn, xsh), x11 = fmaf(t_hi, -sn, xsh);
        const float y00 = fmaf(t_lo, cs, ysl), y01 = fmaf(t_hi, cs, ysl);
        const float y10 = fmaf(t_lo, cs, ysh), y11 = fmaf(t_hi, cs, ysh);
        const int bx = (int)floorf(fminf(fminf(x00, x01), fminf(x10, x11)));
        const int by = (int)floorf(fminf(fminf(y00, y01), fminf(y10, y11)));
        bxs = min(max(bx, -1), 210);
        bys = min(max(by, -1), 210);
        interior = (bx >= 0) && (by >= 0) && (bx <= 210) && (by <= 210);
    };

    // stage 47 rows x 47 cols; gx,gy in [0,257] of padded source by construction
    auto stage = [&](int bxs, int bys) {
#pragma unroll
        for (int k = 0; k < 12; ++k) {
            const int row = wave + 4 * k;  // 0..47
            if (row < LH && lane < 47) {
                const uint4* gp = gbuf + (size_t)(bys + row + 1) * GW + (bxs + 1) + lane;
                dma16(gp, &tile[row * LWr]);
            }
        }
    };

    float accf[NB];
#pragma unroll
    for (int b = 0; b < NB; ++b) accf[b] = 0.f;
    const __half2 hz = __float2half2_rn(0.f);

    int bxs, bys;
    bool interior;
    window(0, bxs, bys, interior);
    stage(bxs, bys);

    for (int ck = 0; ck < NCHUNK; ++ck) {
        __syncthreads();  // DMA of chunk ck drained

        const float t_lo = (float)(ck * CHUNK_T) - C;
        __half2 acc01 = hz, acc23 = hz, acc45 = hz, acc67 = hz;

        // pair-batched sampling: 2 samples' addr+weights, 8 independent
        // ds_read_b128, then 32 packed FMAs. Named scalars only (no spill).
        auto samp2 = [&](float ttA, float ttB, bool chk) {
            const float xA = fmaf(ttA, -sn, xs), yA = fmaf(ttA, cs, ys);
            const float xB = fmaf(ttB, -sn, xs), yB = fmaf(ttB, cs, ys);
            const float xfA = floorf(xA), yfA = floorf(yA);
            const float xfB = floorf(xB), yfB = floorf(yB);
            const int u0A = (int)xfA, v0A = (int)yfA;
            const int u0B = (int)xfB, v0B = (int)yfB;
            const bool okA = !chk || (u0A >= -1 && u0A <= 255 && v0A >= -1 && v0A <= 255);
            const bool okB = !chk || (u0B >= -1 && u0B <= 255 && v0B >= -1 && v0B <= 255);
            const float mA = okA ? 1.f : 0.f;  // OOB sample contributes 0 (ref semantics)
            const float mB = okB ? 1.f : 0.f;
            const float wuA = xA - xfA, wvA = yA - yfA;
            const float wuB = xB - xfB, wvB = yB - yfB;
            const float auA = 1.f - wuA, avA = mA * (1.f - wvA), wvmA = mA * wvA;
            const float auB = 1.f - wuB, avB = mB * (1.f - wvB), wvmB = mB * wvB;
            const __half2 w00A = __float2half2_rn(auA * avA);
            const __half2 w10A = __float2half2_rn(wuA * avA);
            const __half2 w01A = __float2half2_rn(auA * wvmA);
            const __half2 w11A = __float2half2_rn(wuA * wvmA);
            const __half2 w00B = __float2half2_rn(auB * avB);
            const __half2 w10B = __float2half2_rn(wuB * avB);
            const __half2 w01B = __float2half2_rn(auB * wvmB);
            const __half2 w11B = __float2half2_rn(wuB * wvmB);
            const int bA = okA ? ((v0A - bys) * LWr + (u0A - bxs)) : 0;
            const int bB = okB ? ((v0B - bys) * LWr + (u0B - bxs)) : 0;
            // 8 independent LDS reads
            const uint4 pA00 = tile[bA];
            const uint4 pA10 = tile[bA + 1];
            const uint4 pA01 = tile[bA + LWr];
            const uint4 pA11 = tile[bA + LWr + 1];
            const uint4 pB00 = tile[bB];
            const uint4 pB10 = tile[bB + 1];
            const uint4 pB01 = tile[bB + LWr];
            const uint4 pB11 = tile[bB + LWr + 1];
            // 32 packed FMAs
            acc01 = __hfma2(w00A, bc_h2(pA00.x), acc01);
            acc01 = __hfma2(w10A, bc_h2(pA10.x), acc01);
            acc01 = __hfma2(w01A, bc_h2(pA01.x), acc01);
            acc01 = __hfma2(w11A, bc_h2(pA11.x), acc01);
            acc23 = __hfma2(w00A, bc_h2(pA00.y), acc23);
            acc23 = __hfma2(w10A, bc_h2(pA10.y), acc23);
            acc23 = __hfma2(w01A, bc_h2(pA01.y), acc23);
            acc23 = __hfma2(w11A, bc_h2(pA11.y), acc23);
            acc45 = __hfma2(w00A, bc_h2(pA00.z), acc45);
            acc45 = __hfma2(w10A, bc_h2(pA10.z), acc45);
            acc45 = __hfma2(w01A, bc_h2(pA01.z), acc45);
            acc45 = __hfma2(w11A, bc_h2(pA11.z), acc45);
            acc67 = __hfma2(w00A, bc_h2(pA00.w), acc67);
            acc67 = __hfma2(w10A, bc_h2(pA10.w), acc67);
            acc67 = __hfma2(w01A, bc_h2(pA01.w), acc67);
            acc67 = __hfma2(w11A, bc_h2(pA11.w), acc67);
            acc01 = __hfma2(w00B, bc_h2(pB00.x), acc01);
            acc01 = __hfma2(w10B, bc_h2(pB10.x), acc01);
            acc01 = __hfma2(w01B, bc_h2(pB01.x), acc01);
            acc01 = __hfma2(w11B, bc_h2(pB11.x), acc01);
            acc23 = __hfma2(w00B, bc_h2(pB00.y), acc23);
            acc23 = __hfma2(w10B, bc_h2(pB10.y), acc23);
            acc23 = __hfma2(w01B, bc_h2(pB01.y), acc23);
            acc23 = __hfma2(w11B, bc_h2(pB11.y), acc23);
            acc45 = __hfma2(w00B, bc_h2(pB00.z), acc45);
            acc45 = __hfma2(w10B, bc_h2(pB10.z), acc45);
            acc45 = __hfma2(w01B, bc_h2(pB01.z), acc45);
            acc45 = __hfma2(w11B, bc_h2(pB11.z), acc45);
            acc67 = __hfma2(w00B, bc_h2(pB00.w), acc67);
            acc67 = __hfma2(w10B, bc_h2(pB10.w), acc67);
            acc67 = __hfma2(w01B, bc_h2(pB01.w), acc67);
            acc67 = __hfma2(w11B, bc_h2(pB11.w), acc67);
        };

        if (interior) {
            samp2(t_lo + (float)tw, t_lo + (float)(tw + 8), false);
            samp2(t_lo + (float)(tw + 16), t_lo + (float)(tw + 24), false);
        } else {
            samp2(t_lo + (float)tw, t_lo + (float)(tw + 8), true);
            samp2(t_lo + (float)(tw + 16), t_lo + (float)(tw + 24), true);
        }

        accf[0] += __low2float(acc01); accf[1] += __high2float(acc01);
        accf[2] += __low2float(acc23); accf[3] += __high2float(acc23);
        accf[4] += __low2float(acc45); accf[5] += __high2float(acc45);
        accf[6] += __low2float(acc67); accf[7] += __high2float(acc67);

        __syncthreads();  // all reads of chunk ck done; safe to overwrite tile

        if (ck + 1 < NCHUNK) {
            window(ck + 1, bxs, bys, interior);
            stage(bxs, bys);
        }
    }

    // ---- reduction: t-phase pair within wave, then 4 waves via LDS ----
#pragma unroll
    for (int b = 0; b < NB; ++b) accf[b] += __shfl_xor(accf[b], 32);

    float4* red4 = (float4*)tile;  // 4 waves x 32 s x 8 b = 4 KB, tile is free
    if (lane < 32) {
        red4[(wave * 32 + lane) * 2 + 0] = make_float4(accf[0], accf[1], accf[2], accf[3]);
        red4[(wave * 32 + lane) * 2 + 1] = make_float4(accf[4], accf[5], accf[6], accf[7]);
    }
    __syncthreads();
    {
        const float* red = (const float*)tile;
        const int b = tid >> 5;   // 0..7
        const int ss = tid & 31;  // 0..31
        const int base = ss * 8 + b;
        const float sum = red[base] + red[256 + base] + red[512 + base] + red[768 + base];
        out[(b * NA + a) * NREZ + blockIdx.y * 32 + ss] = sum;
    }
}

// -------- fallback (ws too small): direct fp32 gather with clamps --------
__global__ __launch_bounds__(256) void radon_plain(const float* __restrict__ img,
                                                   const float* __restrict__ angles,
                                                   float* __restrict__ out) {
    const int a = blockIdx.x;
    const int tid = threadIdx.x;
    const int wave = tid >> 6;
    const int lane = tid & 63;
    const int s_sub = lane & 7;
    const int t_sub = lane >> 3;
    const int sIdx = blockIdx.y * 32 + wave * 8 + s_sub;
    const float c = 127.5f;
    float sn, cs;
    sincosf(angles[a], &sn, &cs);
    const float s = (float)sIdx - c;
    float acc[NB];
#pragma unroll
    for (int b = 0; b < NB; ++b) acc[b] = 0.f;
    for (int j = 0; j < NREZ / 8; ++j) {
        const float tt = (float)(t_sub + 8 * j) - c;
        const float x = s * cs - tt * sn + c;
        const float y = s * sn + tt * cs + c;
        const float xf = floorf(x), yf = floorf(y);
        const int u0 = (int)xf, v0 = (int)yf;
        if (u0 < -1 || u0 >= NREZ || v0 < -1 || v0 >= NREZ) continue;
        const float wu = x - xf, wv = y - yf;
        const bool iu0 = (u0 >= 0), iu1 = (u0 + 1 <= NREZ - 1);
        const bool iv0 = (v0 >= 0), iv1 = (v0 + 1 <= NREZ - 1);
        const float w00 = (1.f - wu) * (1.f - wv) * ((iu0 && iv0) ? 1.f : 0.f);
        const float w10 = wu * (1.f - wv) * ((iu1 && iv0) ? 1.f : 0.f);
        const float w01 = (1.f - wu) * wv * ((iu0 && iv1) ? 1.f : 0.f);
        const float w11 = wu * wv * ((iu1 && iv1) ? 1.f : 0.f);
        const int u0c = min(max(u0, 0), NREZ - 1);
        const int u1c = min(u0 + 1, NREZ - 1);
        const int v0c = min(max(v0, 0), NREZ - 1);
        const int v1c = min(v0 + 1, NREZ - 1);
#pragma unroll
        for (int b = 0; b < NB; ++b) {
            const float* p = img + b * (NREZ * NREZ);
            acc[b] += w00 * p[v0c * NREZ + u0c] + w10 * p[v0c * NREZ + u1c] +
                      w01 * p[v1c * NREZ + u0c] + w11 * p[v1c * NREZ + u1c];
        }
    }
#pragma unroll
    for (int b = 0; b < NB; ++b) {
        float v = acc[b];
        v += __shfl_xor(v, 8);
        v += __shfl_xor(v, 16);
        v += __shfl_xor(v, 32);
        acc[b] = v;
    }
    if (t_sub == 0) {
#pragma unroll
        for (int b = 0; b < NB; ++b) out[(b * NA + a) * NREZ + sIdx] = acc[b];
    }
}

extern "C" void kernel_launch(void* const* d_in, const int* in_sizes, int n_in,
                              void* d_out, int out_size, void* d_ws, size_t ws_size,
                              hipStream_t stream) {
    (void)in_sizes; (void)n_in; (void)out_size;
    const float* imgs = (const float*)d_in[0];
    const float* angles = (const float*)d_in[1];
    float* out = (float*)d_out;

    dim3 grid(NA, NREZ / 32);
    if (ws_size >= GBYTES) {
        uint4* gbuf = (uint4*)d_ws;
        build_fp16g<<<GW, 256, 0, stream>>>(imgs, gbuf);  // fused guard-zeroing
        radon_dma<<<grid, 256, 0, stream>>>(gbuf, angles, out);
    } else {
        radon_plain<<<grid, 256, 0, stream>>>(imgs, angles, out);
    }
}

// Round 15
// 90.091 us; speedup vs baseline: 1.1984x; 1.0102x over previous
//
#include <hip/hip_runtime.h>
#include <hip/hip_fp16.h>

#define NREZ 256
#define NB 8
#define NA 180

// guarded interleaved source: 258x258 pixels of 16B (8 x fp16), 1-px zero border
#define GW 258
#define GBYTES ((size_t)GW * GW * 16)  /* 1,065,024 B */

// LDS tile: 47 rows x LWr-pixel stride, LWr chosen PER ANGLE from [47,52] so the
// per-lane address step sigma = sn*LWr + cs (pixels, 16B) is far from even mod 2
// -> 32 linear-stepping lanes spread ~uniformly over the 8 bank groups.
// (R10 configuration — measured optimum across R4..R14.)
#define LWMAX 52
#define LH 47
#define CHUNK_T 32
#define NCHUNK (NREZ / CHUNK_T)

__device__ __forceinline__ __half2 bc_h2(unsigned int v) {
    return __builtin_bit_cast(__half2, v);
}

__device__ __forceinline__ void dma16(const uint4* g, uint4* l) {
    // dest is wave-uniform base; HW scatters lane i to base + i*16 (verified R6-R14)
    __builtin_amdgcn_global_load_lds(
        (const __attribute__((address_space(1))) void*)g,
        (__attribute__((address_space(3))) void*)l, 16, 0, 0);
}

// interleave 8 batches -> fp16 uint4 pixel at guard offset (+1,+1); border -> 0
__global__ __launch_bounds__(256) void build_fp16g(const float* __restrict__ img,
                                                   uint4* __restrict__ gbuf) {
    const int gy = blockIdx.x;  // 0..257
    for (int gx = threadIdx.x; gx < GW; gx += 256) {
        uint4 v = make_uint4(0u, 0u, 0u, 0u);
        const int x = gx - 1, y = gy - 1;
        if (x >= 0 && x < NREZ && y >= 0 && y < NREZ) {
            const int p = (y << 8) + x;
            unsigned short h[NB];
#pragma unroll
            for (int b = 0; b < NB; ++b)
                h[b] = __half_as_ushort(__float2half_rn(img[b * (NREZ * NREZ) + p]));
            v.x = (unsigned)h[0] | ((unsigned)h[1] << 16);
            v.y = (unsigned)h[2] | ((unsigned)h[3] << 16);
            v.z = (unsigned)h[4] | ((unsigned)h[5] << 16);
            v.w = (unsigned)h[6] | ((unsigned)h[7] << 16);
        }
        gbuf[(size_t)gy * GW + gx] = v;
    }
}

__global__ __launch_bounds__(256, 4) void radon_dma(const uint4* __restrict__ gbuf,
                                                    const float* __restrict__ angles,
                                                    float* __restrict__ out) {
    __shared__ uint4 tile[LWMAX * LH];  // 39,104 B -> 4 blocks/CU (16 waves)

    const int a = blockIdx.x;
    const int tid = threadIdx.x;
    const int wave = tid >> 6;
    const int lane = tid & 63;
    const int ls = lane & 31;   // s within the block's 32-s strip
    const int lp = lane >> 5;   // t phase (0/1)
    const int sIdx = blockIdx.y * 32 + ls;
    const int tw = 2 * wave + lp;  // wave+phase t-offset: 0..7

    const float C = 127.5f;
    float sn, cs;
    sincosf(angles[a], &sn, &cs);

    // per-angle row stride: maximize margin of (sn*LW + cs) mod 2 from even
    int LWr = 47;
    {
        float best = -1.f;
#pragma unroll
        for (int w = 47; w <= LWMAX; ++w) {
            const float sig = fmaf(sn, (float)w, cs);
            const float u = sig - 2.f * floorf(sig * 0.5f);  // [0,2)
            const float m = 1.f - fabsf(u - 1.f);            // 1 = odd (perfect)
            if (m > best) { best = m; LWr = w; }
        }
    }

    const float s = (float)sIdx - C;
    const float xs = fmaf(s, cs, C);  // x = fmaf(tt,-sn,xs)
    const float ys = fmaf(s, sn, C);  // y = fmaf(tt, cs,ys)

    // block-uniform s extremes; SAME fmaf chain as per-lane math (fp-monotone)
    const float s_lo = (float)(blockIdx.y * 32) - C;
    const float s_hi = s_lo + 31.f;
    const float xsl = fmaf(s_lo, cs, C), xsh = fmaf(s_hi, cs, C);
    const float ysl = fmaf(s_lo, sn, C), ysh = fmaf(s_hi, sn, C);

    // bbox of chunk ck: corner span <= 31(|cs|+|sn|) <= 43.9 -> u0,v0 in [b?, b?+44],
    // +1 corner -> 46 px; 47 staged cols/rows cover all cases incl. edge clamps
    // (bxs=210: dx = u0-210 <= 45, dx+1 = 46). gx = bxs+1+lane <= 210+1+46 = 257 ok.
    auto window = [&](int ck, int& bxs, int& bys, bool& interior) {
        const float t_lo = (float)(ck * CHUNK_T) - C;
        const float t_hi = t_lo + 31.f;
        const float x00 = fmaf(t_lo, -sn, xsl), x01 = fmaf(t_hi, -sn, xsl);
        const float x10 = fmaf(t_lo, -sn, xsh), x11 = fmaf(t_hi, -sn, xsh);
        const float y00 = fmaf(t_lo, cs, ysl), y01 = fmaf(t_hi, cs, ysl);
        const float y10 = fmaf(t_lo, cs, ysh), y11 = fmaf(t_hi, cs, ysh);
        const int bx = (int)floorf(fminf(fminf(x00, x01), fminf(x10, x11)));
        const int by = (int)floorf(fminf(fminf(y00, y01), fminf(y10, y11)));
        bxs = min(max(bx, -1), 210);
        bys = min(max(by, -1), 210);
        interior = (bx >= 0) && (by >= 0) && (bx <= 210) && (by <= 210);
    };

    // stage 47 rows x 47 cols; gx,gy in [0,257] of padded source by construction
    auto stage = [&](int bxs, int bys) {
#pragma unroll
        for (int k = 0; k < 12; ++k) {
            const int row = wave + 4 * k;  // 0..47
            if (row < LH && lane < 47) {
                const uint4* gp = gbuf + (size_t)(bys + row + 1) * GW + (bxs + 1) + lane;
                dma16(gp, &tile[row * LWr]);
            }
        }
    };

    float accf[NB];
#pragma unroll
    for (int b = 0; b < NB; ++b) accf[b] = 0.f;
    const __half2 hz = __float2half2_rn(0.f);

    int bxs, bys;
    bool interior;
    window(0, bxs, bys, interior);
    stage(bxs, bys);

    for (int ck = 0; ck < NCHUNK; ++ck) {
        __syncthreads();  // DMA of chunk ck drained

        const float t_lo = (float)(ck * CHUNK_T) - C;
        __half2 acc01 = hz, acc23 = hz, acc45 = hz, acc67 = hz;

        auto samp = [&](float tt, bool chk) {
            const float x = fmaf(tt, -sn, xs);
            const float y = fmaf(tt, cs, ys);
            const float xf = floorf(x), yf = floorf(y);
            const int u0 = (int)xf, v0 = (int)yf;
            if (!chk || (u0 >= -1 && u0 <= 255 && v0 >= -1 && v0 <= 255)) {
                const float wu = x - xf, wv = y - yf;
                const float au = 1.f - wu, av = 1.f - wv;
                const __half2 w00 = __float2half2_rn(au * av);
                const __half2 w10 = __float2half2_rn(wu * av);
                const __half2 w01 = __float2half2_rn(au * wv);
                const __half2 w11 = __float2half2_rn(wu * wv);
                const int dx = u0 - bxs;  // in [0, 45]
                const int r = v0 - bys;   // in [0, 45]
                const int b00 = r * LWr + dx;
                const int b10 = b00 + LWr;
                const uint4 p00 = tile[b00];
                const uint4 p10 = tile[b00 + 1];
                const uint4 p01 = tile[b10];
                const uint4 p11 = tile[b10 + 1];
                acc01 = __hfma2(w00, bc_h2(p00.x), acc01);
                acc01 = __hfma2(w10, bc_h2(p10.x), acc01);
                acc01 = __hfma2(w01, bc_h2(p01.x), acc01);
                acc01 = __hfma2(w11, bc_h2(p11.x), acc01);
                acc23 = __hfma2(w00, bc_h2(p00.y), acc23);
                acc23 = __hfma2(w10, bc_h2(p10.y), acc23);
                acc23 = __hfma2(w01, bc_h2(p01.y), acc23);
                acc23 = __hfma2(w11, bc_h2(p11.y), acc23);
                acc45 = __hfma2(w00, bc_h2(p00.z), acc45);
                acc45 = __hfma2(w10, bc_h2(p10.z), acc45);
                acc45 = __hfma2(w01, bc_h2(p01.z), acc45);
                acc45 = __hfma2(w11, bc_h2(p11.z), acc45);
                acc67 = __hfma2(w00, bc_h2(p00.w), acc67);
                acc67 = __hfma2(w10, bc_h2(p10.w), acc67);
                acc67 = __hfma2(w01, bc_h2(p01.w), acc67);
                acc67 = __hfma2(w11, bc_h2(p11.w), acc67);
            }
        };

        if (interior) {
#pragma unroll
            for (int it = 0; it < 4; ++it)
                samp(t_lo + (float)(tw + 8 * it), false);
        } else {
#pragma unroll
            for (int it = 0; it < 4; ++it)
                samp(t_lo + (float)(tw + 8 * it), true);
        }

        accf[0] += __low2float(acc01); accf[1] += __high2float(acc01);
        accf[2] += __low2float(acc23); accf[3] += __high2float(acc23);
        accf[4] += __low2float(acc45); accf[5] += __high2float(acc45);
        accf[6] += __low2float(acc67); accf[7] += __high2float(acc67);

        __syncthreads();  // all reads of chunk ck done; safe to overwrite tile

        if (ck + 1 < NCHUNK) {
            window(ck + 1, bxs, bys, interior);
            stage(bxs, bys);
        }
    }

    // ---- reduction: t-phase pair within wave, then 4 waves via LDS ----
#pragma unroll
    for (int b = 0; b < NB; ++b) accf[b] += __shfl_xor(accf[b], 32);

    float4* red4 = (float4*)tile;  // 4 waves x 32 s x 8 b = 4 KB, tile is free
    if (lane < 32) {
        red4[(wave * 32 + lane) * 2 + 0] = make_float4(accf[0], accf[1], accf[2], accf[3]);
        red4[(wave * 32 + lane) * 2 + 1] = make_float4(accf[4], accf[5], accf[6], accf[7]);
    }
    __syncthreads();
    {
        const float* red = (const float*)tile;
        const int b = tid >> 5;   // 0..7
        const int ss = tid & 31;  // 0..31
        const int base = ss * 8 + b;
        const float sum = red[base] + red[256 + base] + red[512 + base] + red[768 + base];
        out[(b * NA + a) * NREZ + blockIdx.y * 32 + ss] = sum;
    }
}

// -------- fallback (ws too small): direct fp32 gather with clamps --------
__global__ __launch_bounds__(256) void radon_plain(const float* __restrict__ img,
                                                   const float* __restrict__ angles,
                                                   float* __restrict__ out) {
    const int a = blockIdx.x;
    const int tid = threadIdx.x;
    const int wave = tid >> 6;
    const int lane = tid & 63;
    const int s_sub = lane & 7;
    const int t_sub = lane >> 3;
    const int sIdx = blockIdx.y * 32 + wave * 8 + s_sub;
    const float c = 127.5f;
    float sn, cs;
    sincosf(angles[a], &sn, &cs);
    const float s = (float)sIdx - c;
    float acc[NB];
#pragma unroll
    for (int b = 0; b < NB; ++b) acc[b] = 0.f;
    for (int j = 0; j < NREZ / 8; ++j) {
        const float tt = (float)(t_sub + 8 * j) - c;
        const float x = s * cs - tt * sn + c;
        const float y = s * sn + tt * cs + c;
        const float xf = floorf(x), yf = floorf(y);
        const int u0 = (int)xf, v0 = (int)yf;
        if (u0 < -1 || u0 >= NREZ || v0 < -1 || v0 >= NREZ) continue;
        const float wu = x - xf, wv = y - yf;
        const bool iu0 = (u0 >= 0), iu1 = (u0 + 1 <= NREZ - 1);
        const bool iv0 = (v0 >= 0), iv1 = (v0 + 1 <= NREZ - 1);
        const float w00 = (1.f - wu) * (1.f - wv) * ((iu0 && iv0) ? 1.f : 0.f);
        const float w10 = wu * (1.f - wv) * ((iu1 && iv0) ? 1.f : 0.f);
        const float w01 = (1.f - wu) * wv * ((iu0 && iv1) ? 1.f : 0.f);
        const float w11 = wu * wv * ((iu1 && iv1) ? 1.f : 0.f);
        const int u0c = min(max(u0, 0), NREZ - 1);
        const int u1c = min(u0 + 1, NREZ - 1);
        const int v0c = min(max(v0, 0), NREZ - 1);
        const int v1c = min(v0 + 1, NREZ - 1);
#pragma unroll
        for (int b = 0; b < NB; ++b) {
            const float* p = img + b * (NREZ * NREZ);
            acc[b] += w00 * p[v0c * NREZ + u0c] + w10 * p[v0c * NREZ + u1c] +
                      w01 * p[v1c * NREZ + u0c] + w11 * p[v1c * NREZ + u1c];
        }
    }
#pragma unroll
    for (int b = 0; b < NB; ++b) {
        float v = acc[b];
        v += __shfl_xor(v, 8);
        v += __shfl_xor(v, 16);
        v += __shfl_xor(v, 32);
        acc[b] = v;
    }
    if (t_sub == 0) {
#pragma unroll
        for (int b = 0; b < NB; ++b) out[(b * NA + a) * NREZ + sIdx] = acc[b];
    }
}

extern "C" void kernel_launch(void* const* d_in, const int* in_sizes, int n_in,
                              void* d_out, int out_size, void* d_ws, size_t ws_size,
                              hipStream_t stream) {
    (void)in_sizes; (void)n_in; (void)out_size;
    const float* imgs = (const float*)d_in[0];
    const float* angles = (const float*)d_in[1];
    float* out = (float*)d_out;

    dim3 grid(NA, NREZ / 32);
    if (ws_size >= GBYTES) {
        uint4* gbuf = (uint4*)d_ws;
        build_fp16g<<<GW, 256, 0, stream>>>(imgs, gbuf);  // fused guard-zeroing
        radon_dma<<<grid, 256, 0, stream>>>(gbuf, angles, out);
    } else {
        radon_plain<<<grid, 256, 0, stream>>>(imgs, angles, out);
    }
}